// Round 1
// baseline (3267.144 us; speedup 1.0000x reference)
//
#include <hip/hip_runtime.h>

#define N_NODES 30000
#define N_EDGES 300000
#define N_TRIP 200000
#define NUM_RELS 8
#define F_RAW 128
#define DDIM 256

// ---------------------------------------------------------------------------
// Classic fp32 tiled GEMM: C[M,N] = A[M,K] @ B[K,N] (+ bias[N] if ADD_BIAS).
// 64x64 tile, BK=16, 256 threads, 4x4 micro-tile per thread.
// ---------------------------------------------------------------------------
template <bool ADD_BIAS>
__global__ __launch_bounds__(256) void sgemm_kernel(
    const float* __restrict__ A, const float* __restrict__ B,
    const float* __restrict__ bias, float* __restrict__ C,
    int M, int N, int K) {
  __shared__ float As[16][64];  // As[k][m]
  __shared__ float Bs[16][64];  // Bs[k][n]

  const int tid = threadIdx.x;      // 0..255
  const int tx = tid & 15;          // n-tile coord
  const int ty = tid >> 4;          // m-tile coord
  const int bm = blockIdx.y * 64;
  const int bn = blockIdx.x * 64;

  float acc[4][4] = {};

  for (int k0 = 0; k0 < K; k0 += 16) {
    // Load A tile: 64 rows x 16 k. Each thread: row=tid/4, k-cols=(tid%4)*4..+3
    const int ar = tid >> 2;
    const int ac = (tid & 3) << 2;
    float4 av = make_float4(0.f, 0.f, 0.f, 0.f);
    if (bm + ar < M)
      av = *reinterpret_cast<const float4*>(&A[(size_t)(bm + ar) * K + k0 + ac]);
    As[ac + 0][ar] = av.x;
    As[ac + 1][ar] = av.y;
    As[ac + 2][ar] = av.z;
    As[ac + 3][ar] = av.w;

    // Load B tile: 16 k-rows x 64 cols. Each thread: row=tid/16, col=(tid%16)*4
    const int br = tid >> 4;
    const int bc = (tid & 15) << 2;
    float4 bv = *reinterpret_cast<const float4*>(&B[(size_t)(k0 + br) * N + bn + bc]);
    *reinterpret_cast<float4*>(&Bs[br][bc]) = bv;

    __syncthreads();

#pragma unroll
    for (int k = 0; k < 16; ++k) {
      float a[4], b[4];
#pragma unroll
      for (int i = 0; i < 4; ++i) a[i] = As[k][ty * 4 + i];
#pragma unroll
      for (int j = 0; j < 4; ++j) b[j] = Bs[k][tx * 4 + j];
#pragma unroll
      for (int i = 0; i < 4; ++i)
#pragma unroll
        for (int j = 0; j < 4; ++j) acc[i][j] += a[i] * b[j];
    }
    __syncthreads();
  }

#pragma unroll
  for (int i = 0; i < 4; ++i) {
    const int row = bm + ty * 4 + i;
    if (row >= M) continue;
#pragma unroll
    for (int j = 0; j < 4; ++j) {
      float v = acc[i][j];
      if (ADD_BIAS) v += bias[bn + tx * 4 + j];
      C[(size_t)row * N + bn + tx * 4 + j] = v;
    }
  }
}

// ---------------------------------------------------------------------------
// Scatter: for edges with etype==rel, h[eb[e]] += y[ea[e]]  (D=256)
// One 64-lane wave per edge; each lane handles 4 floats (float4 read,
// 4 scalar atomicAdds).
// ---------------------------------------------------------------------------
__global__ __launch_bounds__(256) void scatter_kernel(
    const float* __restrict__ y, const int* __restrict__ ea,
    const int* __restrict__ eb, const int* __restrict__ et, int rel, int E,
    float* __restrict__ h) {
  const int e = blockIdx.x * 4 + (threadIdx.x >> 6);
  if (e >= E) return;
  if (et[e] != rel) return;
  const int lane = threadIdx.x & 63;
  const int a = ea[e];
  const int b = eb[e];
  const float4 v =
      *reinterpret_cast<const float4*>(&y[(size_t)a * DDIM + lane * 4]);
  float* d = &h[(size_t)b * DDIM + lane * 4];
  atomicAdd(d + 0, v.x);
  atomicAdd(d + 1, v.y);
  atomicAdd(d + 2, v.z);
  atomicAdd(d + 3, v.w);
}

// ---------------------------------------------------------------------------
// DistMult scoring: weights[t] = sum_d h[s][d] * wrel[r][d] * h[o][d]
// One 64-lane wave per triple, float4 per lane, shuffle reduce.
// ---------------------------------------------------------------------------
__global__ __launch_bounds__(256) void score_kernel(
    const float* __restrict__ h, const float* __restrict__ wrel,
    const int* __restrict__ ts, const int* __restrict__ tr,
    const int* __restrict__ to, float* __restrict__ out, int T) {
  const int t = blockIdx.x * 4 + (threadIdx.x >> 6);
  if (t >= T) return;
  const int lane = threadIdx.x & 63;
  const int s = ts[t];
  const int r = tr[t];
  const int o = to[t];
  const float4 hs =
      *reinterpret_cast<const float4*>(&h[(size_t)s * DDIM + lane * 4]);
  const float4 ho =
      *reinterpret_cast<const float4*>(&h[(size_t)o * DDIM + lane * 4]);
  const float4 wr =
      *reinterpret_cast<const float4*>(&wrel[(size_t)r * DDIM + lane * 4]);
  float sum = hs.x * wr.x * ho.x + hs.y * wr.y * ho.y + hs.z * wr.z * ho.z +
              hs.w * wr.w * ho.w;
#pragma unroll
  for (int off = 32; off; off >>= 1) sum += __shfl_down(sum, off, 64);
  if (lane == 0) out[t] = sum;
}

extern "C" void kernel_launch(void* const* d_in, const int* in_sizes, int n_in,
                              void* d_out, int out_size, void* d_ws,
                              size_t ws_size, hipStream_t stream) {
  const float* feats = (const float*)d_in[0];
  const float* W_affine = (const float*)d_in[1];
  const float* b_affine = (const float*)d_in[2];
  const float* W_fwd = (const float*)d_in[3];
  const float* W_bwd = (const float*)d_in[4];
  const float* W_loop = (const float*)d_in[5];
  const float* w_relation = (const float*)d_in[6];
  const int* src = (const int*)d_in[7];
  const int* dst = (const int*)d_in[8];
  const int* etype = (const int*)d_in[9];
  const int* trip_s = (const int*)d_in[10];
  const int* trip_r = (const int*)d_in[11];
  const int* trip_o = (const int*)d_in[12];

  float* out_w = (float*)d_out;              // [N_TRIP]
  float* h = out_w + N_TRIP;                 // [N_NODES * D]
  float* x = (float*)d_ws;                   // [N_NODES * D]
  float* y = x + (size_t)N_NODES * DDIM;     // [N_NODES * D]

  const dim3 gemm_grid(DDIM / 64, (N_NODES + 63) / 64);

  // x = feats @ W_affine + b_affine
  sgemm_kernel<true><<<gemm_grid, 256, 0, stream>>>(feats, W_affine, b_affine,
                                                    x, N_NODES, DDIM, F_RAW);
  // h = x @ W_loop   (initializes h; scatters accumulate on top)
  sgemm_kernel<false><<<gemm_grid, 256, 0, stream>>>(x, W_loop, nullptr, h,
                                                     N_NODES, DDIM, DDIM);

  const int scat_grid = (N_EDGES + 3) / 4;
  for (int r = 0; r < NUM_RELS; ++r) {
    // forward: y = x @ W_fwd[r];  h[dst] += y[src] for etype==r
    sgemm_kernel<false><<<gemm_grid, 256, 0, stream>>>(
        x, W_fwd + (size_t)r * DDIM * DDIM, nullptr, y, N_NODES, DDIM, DDIM);
    scatter_kernel<<<scat_grid, 256, 0, stream>>>(y, src, dst, etype, r,
                                                  N_EDGES, h);
    // backward: y = x @ W_bwd[r]; h[src] += y[dst] for etype==r
    sgemm_kernel<false><<<gemm_grid, 256, 0, stream>>>(
        x, W_bwd + (size_t)r * DDIM * DDIM, nullptr, y, N_NODES, DDIM, DDIM);
    scatter_kernel<<<scat_grid, 256, 0, stream>>>(y, dst, src, etype, r,
                                                  N_EDGES, h);
  }

  score_kernel<<<(N_TRIP + 3) / 4, 256, 0, stream>>>(
      h, w_relation, trip_s, trip_r, trip_o, out_w, N_TRIP);
}

// Round 2
// 1420.978 us; speedup vs baseline: 2.2992x; 2.2992x over previous
//
#include <hip/hip_runtime.h>

#define N_NODES 30000
#define N_EDGES 300000
#define N_TRIP 200000
#define NUM_RELS 8
#define F_RAW 128
#define DDIM 256

#define NBUCK (2 * NUM_RELS * N_NODES)                    // 480000 buckets
#define SCAN_CHUNK 1024
#define NCHUNK ((NBUCK + SCAN_CHUNK - 1) / SCAN_CHUNK)    // 469
#define NPAD (NCHUNK * SCAN_CHUNK)                        // 480256

// ---------------------------------------------------------------------------
// Classic fp32 tiled GEMM: C[M,N] = A[M,K] @ B[K,N] (+ bias[N] if ADD_BIAS).
// 64x64 tile, BK=16, 256 threads, 4x4 micro-tile per thread.
// ---------------------------------------------------------------------------
template <bool ADD_BIAS>
__global__ __launch_bounds__(256) void sgemm_kernel(
    const float* __restrict__ A, const float* __restrict__ B,
    const float* __restrict__ bias, float* __restrict__ C,
    int M, int N, int K) {
  __shared__ float As[16][64];  // As[k][m]
  __shared__ float Bs[16][64];  // Bs[k][n]

  const int tid = threadIdx.x;
  const int tx = tid & 15;
  const int ty = tid >> 4;
  const int bm = blockIdx.y * 64;
  const int bn = blockIdx.x * 64;

  float acc[4][4] = {};

  for (int k0 = 0; k0 < K; k0 += 16) {
    const int ar = tid >> 2;
    const int ac = (tid & 3) << 2;
    float4 av = make_float4(0.f, 0.f, 0.f, 0.f);
    if (bm + ar < M)
      av = *reinterpret_cast<const float4*>(&A[(size_t)(bm + ar) * K + k0 + ac]);
    As[ac + 0][ar] = av.x;
    As[ac + 1][ar] = av.y;
    As[ac + 2][ar] = av.z;
    As[ac + 3][ar] = av.w;

    const int br = tid >> 4;
    const int bc = (tid & 15) << 2;
    float4 bv = *reinterpret_cast<const float4*>(&B[(size_t)(k0 + br) * N + bn + bc]);
    *reinterpret_cast<float4*>(&Bs[br][bc]) = bv;

    __syncthreads();

#pragma unroll
    for (int k = 0; k < 16; ++k) {
      float a[4], b[4];
#pragma unroll
      for (int i = 0; i < 4; ++i) a[i] = As[k][ty * 4 + i];
#pragma unroll
      for (int j = 0; j < 4; ++j) b[j] = Bs[k][tx * 4 + j];
#pragma unroll
      for (int i = 0; i < 4; ++i)
#pragma unroll
        for (int j = 0; j < 4; ++j) acc[i][j] += a[i] * b[j];
    }
    __syncthreads();
  }

#pragma unroll
  for (int i = 0; i < 4; ++i) {
    const int row = bm + ty * 4 + i;
    if (row >= M) continue;
#pragma unroll
    for (int j = 0; j < 4; ++j) {
      float v = acc[i][j];
      if (ADD_BIAS) v += bias[bn + tx * 4 + j];
      C[(size_t)row * N + bn + tx * 4 + j] = v;
    }
  }
}

// ---------------------------------------------------------------------------
// Edge bucketing: counting sort by (relation, endpoint), both directions.
// Bucket key layout: fwd  key = r*N_NODES + dst   in [0, 240000)
//                    bwd  key = 240000 + r*N_NODES + src in [240000, 480000)
// ---------------------------------------------------------------------------
__global__ void zero_int_kernel(int* __restrict__ p, int n) {
  int i = blockIdx.x * blockDim.x + threadIdx.x;
  if (i < n) p[i] = 0;
}

__global__ void hist_kernel(const int* __restrict__ src,
                            const int* __restrict__ dst,
                            const int* __restrict__ et, int* __restrict__ cnt) {
  int e = blockIdx.x * blockDim.x + threadIdx.x;
  if (e >= N_EDGES) return;
  int r = et[e];
  atomicAdd(&cnt[r * N_NODES + dst[e]], 1);
  atomicAdd(&cnt[NUM_RELS * N_NODES + r * N_NODES + src[e]], 1);
}

__global__ __launch_bounds__(256) void scan1_kernel(const int* __restrict__ cnt,
                                                    int* __restrict__ offs,
                                                    int* __restrict__ bsum) {
  __shared__ int s[256];
  const int b = blockIdx.x, t = threadIdx.x;
  const int base = b * SCAN_CHUNK + t * 4;
  int4 v = *reinterpret_cast<const int4*>(&cnt[base]);
  int tsum = v.x + v.y + v.z + v.w;
  s[t] = tsum;
  __syncthreads();
  for (int off = 1; off < 256; off <<= 1) {
    int x = (t >= off) ? s[t - off] : 0;
    __syncthreads();
    s[t] += x;
    __syncthreads();
  }
  int excl = s[t] - tsum;  // exclusive prefix of this thread's 4 elems
  offs[base + 0] = excl;
  offs[base + 1] = excl + v.x;
  offs[base + 2] = excl + v.x + v.y;
  offs[base + 3] = excl + v.x + v.y + v.z;
  if (t == 0) bsum[b] = s[255];
}

__global__ __launch_bounds__(512) void scan2_kernel(int* __restrict__ bsum) {
  __shared__ int s[512];
  const int t = threadIdx.x;
  int v = (t < NCHUNK) ? bsum[t] : 0;
  s[t] = v;
  __syncthreads();
  for (int off = 1; off < 512; off <<= 1) {
    int x = (t >= off) ? s[t - off] : 0;
    __syncthreads();
    s[t] += x;
    __syncthreads();
  }
  if (t < NCHUNK) bsum[t] = s[t] - v;  // exclusive
}

__global__ void scan3_kernel(int* __restrict__ offs, const int* __restrict__ bsum,
                             int* __restrict__ cur) {
  int i = blockIdx.x * blockDim.x + threadIdx.x;
  if (i >= NPAD) return;
  int v = offs[i] + bsum[i / SCAN_CHUNK];
  offs[i] = v;
  if (i < NBUCK) cur[i] = v;
}

__global__ void fill_kernel(const int* __restrict__ src,
                            const int* __restrict__ dst,
                            const int* __restrict__ et, int* __restrict__ cur,
                            int* __restrict__ sorted) {
  int e = blockIdx.x * blockDim.x + threadIdx.x;
  if (e >= N_EDGES) return;
  int r = et[e];
  int p1 = atomicAdd(&cur[r * N_NODES + dst[e]], 1);
  sorted[p1] = e;
  int p2 = atomicAdd(&cur[NUM_RELS * N_NODES + r * N_NODES + src[e]], 1);
  sorted[p2] = e;
}

// ---------------------------------------------------------------------------
// Gather-accumulate for relation `rel`, both directions fused.
// One 64-lane wave per destination node; registers accumulate float4/lane;
// single non-atomic h-row read-modify-write (buckets disjoint per dispatch).
// ---------------------------------------------------------------------------
__global__ __launch_bounds__(256) void gather_kernel(
    const float* __restrict__ yf, const float* __restrict__ yb,
    const int* __restrict__ src, const int* __restrict__ dst,
    const int* __restrict__ offs, const int* __restrict__ sorted, int rel,
    float* __restrict__ h) {
  const int v = blockIdx.x * 4 + (threadIdx.x >> 6);
  if (v >= N_NODES) return;
  const int lane = threadIdx.x & 63;
  const int kf = rel * N_NODES + v;
  const int kb = NUM_RELS * N_NODES + rel * N_NODES + v;
  const int sf = offs[kf], ef = offs[kf + 1];
  const int sb = offs[kb], eb = offs[kb + 1];
  if (sf == ef && sb == eb) return;

  float ax = 0.f, ay = 0.f, az = 0.f, aw = 0.f;
  for (int i = sf; i < ef; ++i) {
    const int e = sorted[i];
    const float4 t =
        *reinterpret_cast<const float4*>(&yf[(size_t)src[e] * DDIM + lane * 4]);
    ax += t.x; ay += t.y; az += t.z; aw += t.w;
  }
  for (int i = sb; i < eb; ++i) {
    const int e = sorted[i];
    const float4 t =
        *reinterpret_cast<const float4*>(&yb[(size_t)dst[e] * DDIM + lane * 4]);
    ax += t.x; ay += t.y; az += t.z; aw += t.w;
  }
  float4* hp = reinterpret_cast<float4*>(&h[(size_t)v * DDIM + lane * 4]);
  float4 hv = *hp;
  hv.x += ax; hv.y += ay; hv.z += az; hv.w += aw;
  *hp = hv;
}

// ---------------------------------------------------------------------------
// DistMult scoring.
// ---------------------------------------------------------------------------
__global__ __launch_bounds__(256) void score_kernel(
    const float* __restrict__ h, const float* __restrict__ wrel,
    const int* __restrict__ ts, const int* __restrict__ tr,
    const int* __restrict__ to, float* __restrict__ out, int T) {
  const int t = blockIdx.x * 4 + (threadIdx.x >> 6);
  if (t >= T) return;
  const int lane = threadIdx.x & 63;
  const int s = ts[t];
  const int r = tr[t];
  const int o = to[t];
  const float4 hs =
      *reinterpret_cast<const float4*>(&h[(size_t)s * DDIM + lane * 4]);
  const float4 ho =
      *reinterpret_cast<const float4*>(&h[(size_t)o * DDIM + lane * 4]);
  const float4 wr =
      *reinterpret_cast<const float4*>(&wrel[(size_t)r * DDIM + lane * 4]);
  float sum = hs.x * wr.x * ho.x + hs.y * wr.y * ho.y + hs.z * wr.z * ho.z +
              hs.w * wr.w * ho.w;
#pragma unroll
  for (int off = 32; off; off >>= 1) sum += __shfl_down(sum, off, 64);
  if (lane == 0) out[t] = sum;
}

extern "C" void kernel_launch(void* const* d_in, const int* in_sizes, int n_in,
                              void* d_out, int out_size, void* d_ws,
                              size_t ws_size, hipStream_t stream) {
  const float* feats = (const float*)d_in[0];
  const float* W_affine = (const float*)d_in[1];
  const float* b_affine = (const float*)d_in[2];
  const float* W_fwd = (const float*)d_in[3];
  const float* W_bwd = (const float*)d_in[4];
  const float* W_loop = (const float*)d_in[5];
  const float* w_relation = (const float*)d_in[6];
  const int* src = (const int*)d_in[7];
  const int* dst = (const int*)d_in[8];
  const int* etype = (const int*)d_in[9];
  const int* trip_s = (const int*)d_in[10];
  const int* trip_r = (const int*)d_in[11];
  const int* trip_o = (const int*)d_in[12];

  float* out_w = (float*)d_out;  // [N_TRIP]
  float* h = out_w + N_TRIP;     // [N_NODES * D]

  // workspace layout
  float* x = (float*)d_ws;                       // [N_NODES*D]
  float* yf = x + (size_t)N_NODES * DDIM;        // [N_NODES*D]
  float* yb = yf + (size_t)N_NODES * DDIM;       // [N_NODES*D]
  int* cnt = (int*)(yb + (size_t)N_NODES * DDIM);  // [NPAD]
  int* offs = cnt + NPAD;                        // [NPAD]
  int* cur = offs + NPAD;                        // [NPAD]
  int* bsum = cur + NPAD;                        // [512]
  int* sorted = bsum + 512;                      // [2*N_EDGES]

  // ---- build edge buckets (counting sort by (rel, endpoint), 2 dirs) ----
  zero_int_kernel<<<(NPAD + 255) / 256, 256, 0, stream>>>(cnt, NPAD);
  hist_kernel<<<(N_EDGES + 255) / 256, 256, 0, stream>>>(src, dst, etype, cnt);
  scan1_kernel<<<NCHUNK, 256, 0, stream>>>(cnt, offs, bsum);
  scan2_kernel<<<1, 512, 0, stream>>>(bsum);
  scan3_kernel<<<(NPAD + 255) / 256, 256, 0, stream>>>(offs, bsum, cur);
  fill_kernel<<<(N_EDGES + 255) / 256, 256, 0, stream>>>(src, dst, etype, cur,
                                                         sorted);

  // ---- GEMMs + gathers ----
  const dim3 gemm_grid(DDIM / 64, (N_NODES + 63) / 64);

  // x = feats @ W_affine + b_affine
  sgemm_kernel<true><<<gemm_grid, 256, 0, stream>>>(feats, W_affine, b_affine,
                                                    x, N_NODES, DDIM, F_RAW);
  // h = x @ W_loop  (initializes h)
  sgemm_kernel<false><<<gemm_grid, 256, 0, stream>>>(x, W_loop, nullptr, h,
                                                     N_NODES, DDIM, DDIM);

  const int gat_grid = (N_NODES + 3) / 4;
  for (int r = 0; r < NUM_RELS; ++r) {
    sgemm_kernel<false><<<gemm_grid, 256, 0, stream>>>(
        x, W_fwd + (size_t)r * DDIM * DDIM, nullptr, yf, N_NODES, DDIM, DDIM);
    sgemm_kernel<false><<<gemm_grid, 256, 0, stream>>>(
        x, W_bwd + (size_t)r * DDIM * DDIM, nullptr, yb, N_NODES, DDIM, DDIM);
    gather_kernel<<<gat_grid, 256, 0, stream>>>(yf, yb, src, dst, offs, sorted,
                                                r, h);
  }

  score_kernel<<<(N_TRIP + 3) / 4, 256, 0, stream>>>(
      h, w_relation, trip_s, trip_r, trip_o, out_w, N_TRIP);
}

// Round 3
// 545.484 us; speedup vs baseline: 5.9894x; 2.6050x over previous
//
#include <hip/hip_runtime.h>

#define N_NODES 30000
#define N_EDGES 300000
#define N_TRIP 200000
#define NUM_RELS 8
#define F_RAW 128
#define DDIM 256

#define NBUCK (2 * NUM_RELS * N_NODES)                    // 480000 buckets
#define SCAN_CHUNK 1024
#define NCHUNK ((NBUCK + SCAN_CHUNK - 1) / SCAN_CHUNK)    // 469
#define NPAD (NCHUNK * SCAN_CHUNK)                        // 480256

typedef __attribute__((ext_vector_type(8))) short short8;
typedef __attribute__((ext_vector_type(4))) float f32x4;

__device__ inline unsigned short f2bf(float f) {
  unsigned u = __builtin_bit_cast(unsigned, f);
  u = (u + 0x7FFFu + ((u >> 16) & 1u)) >> 16;
  return (unsigned short)u;
}
__device__ inline float bf2f(unsigned short s) {
  unsigned u = ((unsigned)s) << 16;
  return __builtin_bit_cast(float, u);
}

// ---------------------------------------------------------------------------
// bf16 MFMA GEMM: C[M,256] = A[M,K] @ Bt[256,K]^T (+bias). K % 64 == 0.
// 128x128 tile, BK=64, 256 threads = 4 waves, each wave a 64x64 quadrant.
// Staging: global_load_lds width=16, linear LDS dest, XOR-swizzled global
// source; ds_read applies the same XOR (rule: both-sides-or-neither).
// ---------------------------------------------------------------------------
template <int OUT_BF16, int ADD_BIAS>
__global__ __launch_bounds__(256) void mfma_gemm_kernel(
    const unsigned short* __restrict__ A, const unsigned short* __restrict__ Bt,
    const float* __restrict__ bias, void* __restrict__ C, int M, int K) {
  __shared__ __align__(16) unsigned short As[128 * 64];  // [row][64 k] swizzled
  __shared__ __align__(16) unsigned short Bs[128 * 64];  // [n][64 k] swizzled

  const int tid = threadIdx.x;
  const int lane = tid & 63;
  const int wave = tid >> 6;
  const int bm = blockIdx.y * 128;
  const int bn = blockIdx.x * 128;
  const int wr = wave >> 1;  // 0..1
  const int wc = wave & 1;   // 0..1

  f32x4 acc[4][4];
#pragma unroll
  for (int i = 0; i < 4; ++i)
#pragma unroll
    for (int j = 0; j < 4; ++j) acc[i][j] = (f32x4){0.f, 0.f, 0.f, 0.f};

  const int g = lane >> 4;    // 0..3 (k-group)
  const int rl = lane & 15;   // row-in-fragment

  for (int k0 = 0; k0 < K; k0 += 64) {
    // ---- stage A (16KB) + B (16KB): 8 chunks of 1KB per wave ----
#pragma unroll
    for (int c = 0; c < 8; ++c) {
      const int chunk = c * 4 + wave;  // wave-uniform
      if (chunk < 16) {
        const int S = chunk * 64 + lane;  // 16B slot in A tile
        const int row = S >> 3;
        const int s = S & 7;
        int grow = bm + row;
        if (grow > M - 1) grow = M - 1;
        const int kcol = k0 + ((s ^ (row & 7)) << 3);
        const unsigned short* gp = A + (size_t)grow * K + kcol;
        unsigned short* lp = As + (size_t)chunk * 512;  // wave-uniform base
        __builtin_amdgcn_global_load_lds(
            (const __attribute__((address_space(1))) void*)gp,
            (__attribute__((address_space(3))) void*)lp, 16, 0, 0);
      } else {
        const int S = (chunk - 16) * 64 + lane;
        const int row = S >> 3;  // n index, always valid (N=256)
        const int s = S & 7;
        const int kcol = k0 + ((s ^ (row & 7)) << 3);
        const unsigned short* gp = Bt + (size_t)(bn + row) * K + kcol;
        unsigned short* lp = Bs + (size_t)(chunk - 16) * 512;
        __builtin_amdgcn_global_load_lds(
            (const __attribute__((address_space(1))) void*)gp,
            (__attribute__((address_space(3))) void*)lp, 16, 0, 0);
      }
    }
    __syncthreads();  // drains vmcnt before barrier (compiler-inserted)

#pragma unroll
    for (int kk = 0; kk < 2; ++kk) {
      short8 a[4], b[4];
#pragma unroll
      for (int mi = 0; mi < 4; ++mi) {
        const int row = wr * 64 + mi * 16 + rl;
        const int slot = (kk * 4 + g) ^ (row & 7);
        a[mi] = *(const short8*)&As[row * 64 + slot * 8];
      }
#pragma unroll
      for (int ni = 0; ni < 4; ++ni) {
        const int row = wc * 64 + ni * 16 + rl;
        const int slot = (kk * 4 + g) ^ (row & 7);
        b[ni] = *(const short8*)&Bs[row * 64 + slot * 8];
      }
#pragma unroll
      for (int mi = 0; mi < 4; ++mi)
#pragma unroll
        for (int ni = 0; ni < 4; ++ni)
          acc[mi][ni] = __builtin_amdgcn_mfma_f32_16x16x32_bf16(
              a[mi], b[ni], acc[mi][ni], 0, 0, 0);
    }
    __syncthreads();
  }

  // ---- epilogue: C/D frag mapping col=lane&15, row=(lane>>4)*4+j ----
#pragma unroll
  for (int mi = 0; mi < 4; ++mi) {
#pragma unroll
    for (int j = 0; j < 4; ++j) {
      const int row = bm + wr * 64 + mi * 16 + g * 4 + j;
      if (row >= M) continue;
#pragma unroll
      for (int ni = 0; ni < 4; ++ni) {
        const int col = bn + wc * 64 + ni * 16 + rl;
        float v = acc[mi][ni][j];
        if (ADD_BIAS) v += bias[col];
        if (OUT_BF16)
          ((unsigned short*)C)[(size_t)row * DDIM + col] = f2bf(v);
        else
          ((float*)C)[(size_t)row * DDIM + col] = v;
      }
    }
  }
}

// ---------------------------------------------------------------------------
// Weight prep: transpose+convert fp32 [R][K][N] -> bf16 [R][N][K]
// ---------------------------------------------------------------------------
__global__ void transpose_bf16_kernel(const float* __restrict__ src,
                                      unsigned short* __restrict__ dst,
                                      int R, int K, int N) {
  const int i = blockIdx.x * blockDim.x + threadIdx.x;
  const int total = R * K * N;
  if (i >= total) return;
  const int r = i / (K * N);
  const int rem = i - r * K * N;
  const int k = rem / N;
  const int n = rem - k * N;
  dst[(size_t)r * K * N + (size_t)n * K + k] = f2bf(src[i]);
}

__global__ void convert_bf16_kernel(const float* __restrict__ src,
                                    unsigned short* __restrict__ dst,
                                    int total) {
  const int i = blockIdx.x * blockDim.x + threadIdx.x;
  if (i < total) dst[i] = f2bf(src[i]);
}

// ---------------------------------------------------------------------------
// Edge bucketing: counting sort by (relation, endpoint), both directions.
// ---------------------------------------------------------------------------
__global__ void zero_int_kernel(int* __restrict__ p, int n) {
  int i = blockIdx.x * blockDim.x + threadIdx.x;
  if (i < n) p[i] = 0;
}

__global__ void hist_kernel(const int* __restrict__ src,
                            const int* __restrict__ dst,
                            const int* __restrict__ et, int* __restrict__ cnt) {
  int e = blockIdx.x * blockDim.x + threadIdx.x;
  if (e >= N_EDGES) return;
  int r = et[e];
  atomicAdd(&cnt[r * N_NODES + dst[e]], 1);
  atomicAdd(&cnt[NUM_RELS * N_NODES + r * N_NODES + src[e]], 1);
}

__global__ __launch_bounds__(256) void scan1_kernel(const int* __restrict__ cnt,
                                                    int* __restrict__ offs,
                                                    int* __restrict__ bsum) {
  __shared__ int s[256];
  const int b = blockIdx.x, t = threadIdx.x;
  const int base = b * SCAN_CHUNK + t * 4;
  int4 v = *reinterpret_cast<const int4*>(&cnt[base]);
  int tsum = v.x + v.y + v.z + v.w;
  s[t] = tsum;
  __syncthreads();
  for (int off = 1; off < 256; off <<= 1) {
    int x = (t >= off) ? s[t - off] : 0;
    __syncthreads();
    s[t] += x;
    __syncthreads();
  }
  int excl = s[t] - tsum;
  offs[base + 0] = excl;
  offs[base + 1] = excl + v.x;
  offs[base + 2] = excl + v.x + v.y;
  offs[base + 3] = excl + v.x + v.y + v.z;
  if (t == 0) bsum[b] = s[255];
}

__global__ __launch_bounds__(512) void scan2_kernel(int* __restrict__ bsum) {
  __shared__ int s[512];
  const int t = threadIdx.x;
  int v = (t < NCHUNK) ? bsum[t] : 0;
  s[t] = v;
  __syncthreads();
  for (int off = 1; off < 512; off <<= 1) {
    int x = (t >= off) ? s[t - off] : 0;
    __syncthreads();
    s[t] += x;
    __syncthreads();
  }
  if (t < NCHUNK) bsum[t] = s[t] - v;
}

__global__ void scan3_kernel(int* __restrict__ offs,
                             const int* __restrict__ bsum,
                             int* __restrict__ cur) {
  int i = blockIdx.x * blockDim.x + threadIdx.x;
  if (i >= NPAD) return;
  int v = offs[i] + bsum[i / SCAN_CHUNK];
  offs[i] = v;
  if (i < NBUCK) cur[i] = v;
}

__global__ void fill_kernel(const int* __restrict__ src,
                            const int* __restrict__ dst,
                            const int* __restrict__ et, int* __restrict__ cur,
                            int* __restrict__ sorted) {
  int e = blockIdx.x * blockDim.x + threadIdx.x;
  if (e >= N_EDGES) return;
  int r = et[e];
  int p1 = atomicAdd(&cur[r * N_NODES + dst[e]], 1);
  sorted[p1] = e;
  int p2 = atomicAdd(&cur[NUM_RELS * N_NODES + r * N_NODES + src[e]], 1);
  sorted[p2] = e;
}

// ---------------------------------------------------------------------------
// Gather-accumulate for relation `rel` (y matrices in bf16), fwd+bwd fused.
// One wave per node; lane handles 4 dims; non-atomic h-row RMW.
// ---------------------------------------------------------------------------
__global__ __launch_bounds__(256) void gather_kernel(
    const unsigned short* __restrict__ yf, const unsigned short* __restrict__ yb,
    const int* __restrict__ src, const int* __restrict__ dst,
    const int* __restrict__ offs, const int* __restrict__ sorted, int rel,
    float* __restrict__ h) {
  const int v = blockIdx.x * 4 + (threadIdx.x >> 6);
  if (v >= N_NODES) return;
  const int lane = threadIdx.x & 63;
  const int kf = rel * N_NODES + v;
  const int kb = NUM_RELS * N_NODES + rel * N_NODES + v;
  const int sf = offs[kf], ef = offs[kf + 1];
  const int sb = offs[kb], eb = offs[kb + 1];
  if (sf == ef && sb == eb) return;

  float ax = 0.f, ay = 0.f, az = 0.f, aw = 0.f;
  for (int i = sf; i < ef; ++i) {
    const int e = sorted[i];
    const ushort4 t =
        *reinterpret_cast<const ushort4*>(&yf[(size_t)src[e] * DDIM + lane * 4]);
    ax += bf2f(t.x); ay += bf2f(t.y); az += bf2f(t.z); aw += bf2f(t.w);
  }
  for (int i = sb; i < eb; ++i) {
    const int e = sorted[i];
    const ushort4 t =
        *reinterpret_cast<const ushort4*>(&yb[(size_t)dst[e] * DDIM + lane * 4]);
    ax += bf2f(t.x); ay += bf2f(t.y); az += bf2f(t.z); aw += bf2f(t.w);
  }
  float4* hp = reinterpret_cast<float4*>(&h[(size_t)v * DDIM + lane * 4]);
  float4 hv = *hp;
  hv.x += ax; hv.y += ay; hv.z += az; hv.w += aw;
  *hp = hv;
}

// ---------------------------------------------------------------------------
// DistMult scoring (fp32 h).
// ---------------------------------------------------------------------------
__global__ __launch_bounds__(256) void score_kernel(
    const float* __restrict__ h, const float* __restrict__ wrel,
    const int* __restrict__ ts, const int* __restrict__ tr,
    const int* __restrict__ to, float* __restrict__ out, int T) {
  const int t = blockIdx.x * 4 + (threadIdx.x >> 6);
  if (t >= T) return;
  const int lane = threadIdx.x & 63;
  const int s = ts[t];
  const int r = tr[t];
  const int o = to[t];
  const float4 hs =
      *reinterpret_cast<const float4*>(&h[(size_t)s * DDIM + lane * 4]);
  const float4 ho =
      *reinterpret_cast<const float4*>(&h[(size_t)o * DDIM + lane * 4]);
  const float4 wr =
      *reinterpret_cast<const float4*>(&wrel[(size_t)r * DDIM + lane * 4]);
  float sum = hs.x * wr.x * ho.x + hs.y * wr.y * ho.y + hs.z * wr.z * ho.z +
              hs.w * wr.w * ho.w;
#pragma unroll
  for (int off = 32; off; off >>= 1) sum += __shfl_down(sum, off, 64);
  if (lane == 0) out[t] = sum;
}

extern "C" void kernel_launch(void* const* d_in, const int* in_sizes, int n_in,
                              void* d_out, int out_size, void* d_ws,
                              size_t ws_size, hipStream_t stream) {
  const float* feats = (const float*)d_in[0];
  const float* W_affine = (const float*)d_in[1];
  const float* b_affine = (const float*)d_in[2];
  const float* W_fwd = (const float*)d_in[3];
  const float* W_bwd = (const float*)d_in[4];
  const float* W_loop = (const float*)d_in[5];
  const float* w_relation = (const float*)d_in[6];
  const int* src = (const int*)d_in[7];
  const int* dst = (const int*)d_in[8];
  const int* etype = (const int*)d_in[9];
  const int* trip_s = (const int*)d_in[10];
  const int* trip_r = (const int*)d_in[11];
  const int* trip_o = (const int*)d_in[12];

  float* out_w = (float*)d_out;  // [N_TRIP]
  float* h = out_w + N_TRIP;     // [N_NODES * D] fp32

  // ---- workspace layout (bytes, all 256-aligned) ----
  char* ws = (char*)d_ws;
  unsigned short* fb = (unsigned short*)(ws);                  // 30000*128 bf16
  unsigned short* xb = (unsigned short*)(ws + 7680000);        // 30000*256 bf16
  unsigned short* yf = (unsigned short*)(ws + 23040000);       // 30000*256 bf16
  unsigned short* yb = (unsigned short*)(ws + 38400000);       // 30000*256 bf16
  unsigned short* Wta = (unsigned short*)(ws + 53760000);      // [256][128]
  unsigned short* Wtf = (unsigned short*)(ws + 53825536);      // [8][256][256]
  unsigned short* Wtb = (unsigned short*)(ws + 54874112);      // [8][256][256]
  unsigned short* Wtl = (unsigned short*)(ws + 55922688);      // [256][256]
  int* cnt = (int*)(ws + 56053760);                            // [NPAD]
  int* offs = (int*)(ws + 57974784);                           // [NPAD]
  int* cur = (int*)(ws + 59895808);                            // [NPAD]
  int* bsum = (int*)(ws + 61816832);                           // [512]
  int* sorted = (int*)(ws + 61818880);                         // [2*N_EDGES]

  // ---- edge bucketing (counting sort) ----
  zero_int_kernel<<<(NPAD + 255) / 256, 256, 0, stream>>>(cnt, NPAD);
  hist_kernel<<<(N_EDGES + 255) / 256, 256, 0, stream>>>(src, dst, etype, cnt);
  scan1_kernel<<<NCHUNK, 256, 0, stream>>>(cnt, offs, bsum);
  scan2_kernel<<<1, 512, 0, stream>>>(bsum);
  scan3_kernel<<<(NPAD + 255) / 256, 256, 0, stream>>>(offs, bsum, cur);
  fill_kernel<<<(N_EDGES + 255) / 256, 256, 0, stream>>>(src, dst, etype, cur,
                                                         sorted);

  // ---- bf16 conversions ----
  convert_bf16_kernel<<<(N_NODES * F_RAW + 255) / 256, 256, 0, stream>>>(
      feats, fb, N_NODES * F_RAW);
  transpose_bf16_kernel<<<(F_RAW * DDIM + 255) / 256, 256, 0, stream>>>(
      W_affine, Wta, 1, F_RAW, DDIM);
  transpose_bf16_kernel<<<(NUM_RELS * DDIM * DDIM + 255) / 256, 256, 0,
                          stream>>>(W_fwd, Wtf, NUM_RELS, DDIM, DDIM);
  transpose_bf16_kernel<<<(NUM_RELS * DDIM * DDIM + 255) / 256, 256, 0,
                          stream>>>(W_bwd, Wtb, NUM_RELS, DDIM, DDIM);
  transpose_bf16_kernel<<<(DDIM * DDIM + 255) / 256, 256, 0, stream>>>(
      W_loop, Wtl, 1, DDIM, DDIM);

  // ---- GEMMs + gathers ----
  const dim3 ggrid(DDIM / 128, (N_NODES + 127) / 128);  // 2 x 235

  // xb = bf16(feats @ W_affine + b)
  mfma_gemm_kernel<1, 1><<<ggrid, 256, 0, stream>>>(fb, Wta, b_affine, xb,
                                                    N_NODES, F_RAW);
  // h = xb @ W_loop (fp32, initializes h)
  mfma_gemm_kernel<0, 0><<<ggrid, 256, 0, stream>>>(xb, Wtl, nullptr, h,
                                                    N_NODES, DDIM);

  const int gat_grid = (N_NODES + 3) / 4;
  for (int r = 0; r < NUM_RELS; ++r) {
    mfma_gemm_kernel<1, 0><<<ggrid, 256, 0, stream>>>(
        xb, Wtf + (size_t)r * DDIM * DDIM, nullptr, yf, N_NODES, DDIM);
    mfma_gemm_kernel<1, 0><<<ggrid, 256, 0, stream>>>(
        xb, Wtb + (size_t)r * DDIM * DDIM, nullptr, yb, N_NODES, DDIM);
    gather_kernel<<<gat_grid, 256, 0, stream>>>(yf, yb, src, dst, offs, sorted,
                                                r, h);
  }

  score_kernel<<<(N_TRIP + 3) / 4, 256, 0, stream>>>(
      h, w_relation, trip_s, trip_r, trip_o, out_w, N_TRIP);
}

// Round 4
// 407.210 us; speedup vs baseline: 8.0232x; 1.3396x over previous
//
#include <hip/hip_runtime.h>

#define N_NODES 30000
#define N_EDGES 300000
#define N_TRIP 200000
#define NUM_RELS 8
#define F_RAW 128
#define DDIM 256

#define NBUCK (2 * NUM_RELS * N_NODES)                    // 480000 buckets
#define SCAN_CHUNK 1024
#define NCHUNK ((NBUCK + SCAN_CHUNK - 1) / SCAN_CHUNK)    // 469
#define NPAD (NCHUNK * SCAN_CHUNK)                        // 480256

#define KBIG 2304   // 8 rel blocks + x/W_loop block
#define KBWD 2048   // 8 rel blocks

typedef __attribute__((ext_vector_type(8))) short short8;
typedef __attribute__((ext_vector_type(4))) float f32x4;

__device__ inline unsigned short f2bf(float f) {
  unsigned u = __builtin_bit_cast(unsigned, f);
  u = (u + 0x7FFFu + ((u >> 16) & 1u)) >> 16;
  return (unsigned short)u;
}
__device__ inline float bf2f(unsigned short s) {
  unsigned u = ((unsigned)s) << 16;
  return __builtin_bit_cast(float, u);
}

// ===========================================================================
// Shared: edge bucketing (counting sort by (rel, endpoint), both directions)
// fwd key = r*N + dst in [0, 240000); bwd key = 240000 + r*N + src
// ===========================================================================
__global__ void zero_int_kernel(int* __restrict__ p, int n) {
  int i = blockIdx.x * blockDim.x + threadIdx.x;
  if (i < n) p[i] = 0;
}

__global__ void hist_kernel(const int* __restrict__ src,
                            const int* __restrict__ dst,
                            const int* __restrict__ et, int* __restrict__ cnt) {
  int e = blockIdx.x * blockDim.x + threadIdx.x;
  if (e >= N_EDGES) return;
  int r = et[e];
  atomicAdd(&cnt[r * N_NODES + dst[e]], 1);
  atomicAdd(&cnt[NUM_RELS * N_NODES + r * N_NODES + src[e]], 1);
}

__global__ __launch_bounds__(256) void scan1_kernel(const int* __restrict__ cnt,
                                                    int* __restrict__ offs,
                                                    int* __restrict__ bsum) {
  __shared__ int s[256];
  const int b = blockIdx.x, t = threadIdx.x;
  const int base = b * SCAN_CHUNK + t * 4;
  int4 v = *reinterpret_cast<const int4*>(&cnt[base]);
  int tsum = v.x + v.y + v.z + v.w;
  s[t] = tsum;
  __syncthreads();
  for (int off = 1; off < 256; off <<= 1) {
    int x = (t >= off) ? s[t - off] : 0;
    __syncthreads();
    s[t] += x;
    __syncthreads();
  }
  int excl = s[t] - tsum;
  offs[base + 0] = excl;
  offs[base + 1] = excl + v.x;
  offs[base + 2] = excl + v.x + v.y;
  offs[base + 3] = excl + v.x + v.y + v.z;
  if (t == 0) bsum[b] = s[255];
}

__global__ __launch_bounds__(512) void scan2_kernel(int* __restrict__ bsum) {
  __shared__ int s[512];
  const int t = threadIdx.x;
  int v = (t < NCHUNK) ? bsum[t] : 0;
  s[t] = v;
  __syncthreads();
  for (int off = 1; off < 512; off <<= 1) {
    int x = (t >= off) ? s[t - off] : 0;
    __syncthreads();
    s[t] += x;
    __syncthreads();
  }
  if (t < NCHUNK) bsum[t] = s[t] - v;
}

__global__ void scan3_kernel(int* __restrict__ offs,
                             const int* __restrict__ bsum,
                             int* __restrict__ cur) {
  int i = blockIdx.x * blockDim.x + threadIdx.x;
  if (i >= NPAD) return;
  int v = offs[i] + bsum[i / SCAN_CHUNK];
  offs[i] = v;
  if (i < NBUCK) cur[i] = v;
}

__global__ void fill_kernel(const int* __restrict__ src,
                            const int* __restrict__ dst,
                            const int* __restrict__ et, int* __restrict__ cur,
                            int* __restrict__ sorted) {
  int e = blockIdx.x * blockDim.x + threadIdx.x;
  if (e >= N_EDGES) return;
  int r = et[e];
  int p1 = atomicAdd(&cur[r * N_NODES + dst[e]], 1);
  sorted[p1] = e;
  int p2 = atomicAdd(&cur[NUM_RELS * N_NODES + r * N_NODES + src[e]], 1);
  sorted[p2] = e;
}

// ===========================================================================
// Shared: conversions
// ===========================================================================
__global__ void transpose_bf16_kernel(const float* __restrict__ src,
                                      unsigned short* __restrict__ dst,
                                      int R, int K, int N) {
  const int i = blockIdx.x * blockDim.x + threadIdx.x;
  const int total = R * K * N;
  if (i >= total) return;
  const int r = i / (K * N);
  const int rem = i - r * K * N;
  const int k = rem / N;
  const int n = rem - k * N;
  dst[(size_t)r * K * N + (size_t)n * K + k] = f2bf(src[i]);
}

__global__ void convert_bf16_kernel(const float* __restrict__ src,
                                    unsigned short* __restrict__ dst,
                                    int total) {
  const int i = blockIdx.x * blockDim.x + threadIdx.x;
  if (i < total) dst[i] = f2bf(src[i]);
}

// Build Wcat [256][KK] bf16: cols kk<2048 from W8[r=kk>>8][k=kk&255][n],
// cols >=2048 (if KK>2048) from Wextra[k][n]. Contiguous writes.
__global__ void build_wcat_kernel(const float* __restrict__ W8,
                                  const float* __restrict__ Wextra,
                                  unsigned short* __restrict__ dst, int KK) {
  const int i = blockIdx.x * blockDim.x + threadIdx.x;
  if (i >= 256 * KK) return;
  const int n = i / KK;
  const int kk = i - n * KK;
  float v;
  if (kk < 2048) {
    const int r = kk >> 8, k = kk & 255;
    v = W8[((size_t)r * 256 + k) * 256 + n];
  } else {
    v = Wextra[(size_t)(kk - 2048) * 256 + n];
  }
  dst[i] = f2bf(v);
}

// ===========================================================================
// FUSED PATH: 512-thread MFMA GEMM, C[M,256] = A[M,K] @ Bt[256,K]^T (+bias).
// BM=128, BN=256 (grid.x covers M), BK=64, 8 waves each 64x64 quadrant.
// OUT_MODE: 0 = write f32; 1 = write bf16; 2 = f32 += acc, also write bf16.
// ===========================================================================
template <int OUT_MODE, int ADD_BIAS>
__global__ __launch_bounds__(512) void gemm256_kernel(
    const unsigned short* __restrict__ A, int lda, int K,
    const unsigned short* __restrict__ Bt, const float* __restrict__ bias,
    float* __restrict__ Cf, unsigned short* __restrict__ Cb, int ldc, int M) {
  __shared__ __align__(16) unsigned short As[128 * 64];
  __shared__ __align__(16) unsigned short Bs[256 * 64];

  const int tid = threadIdx.x;
  const int lane = tid & 63;
  const int wave = tid >> 6;  // 0..7
  const int wr = wave >> 2;   // 0..1
  const int wc = wave & 3;    // 0..3
  const int bm = blockIdx.x * 128;
  const int g = lane >> 4;    // 0..3
  const int rl = lane & 15;

  f32x4 acc[4][4];
#pragma unroll
  for (int i = 0; i < 4; ++i)
#pragma unroll
    for (int j = 0; j < 4; ++j) acc[i][j] = (f32x4){0.f, 0.f, 0.f, 0.f};

  for (int k0 = 0; k0 < K; k0 += 64) {
    // stage A (16 chunks x 1KB) + B (32 chunks): 6 chunks per wave
#pragma unroll
    for (int c = 0; c < 6; ++c) {
      const int chunk = c * 8 + wave;  // wave-uniform
      if (chunk < 16) {
        const int S = chunk * 64 + lane;
        const int row = S >> 3;
        const int s = S & 7;
        int grow = bm + row;
        if (grow > M - 1) grow = M - 1;
        const unsigned short* gp =
            A + (size_t)grow * lda + k0 + ((s ^ (row & 7)) << 3);
        unsigned short* lp = As + (size_t)chunk * 512;
        __builtin_amdgcn_global_load_lds(
            (const __attribute__((address_space(1))) void*)gp,
            (__attribute__((address_space(3))) void*)lp, 16, 0, 0);
      } else {
        const int S = (chunk - 16) * 64 + lane;
        const int row = S >> 3;  // 0..255
        const int s = S & 7;
        const unsigned short* gp =
            Bt + (size_t)row * K + k0 + ((s ^ (row & 7)) << 3);
        unsigned short* lp = Bs + (size_t)(chunk - 16) * 512;
        __builtin_amdgcn_global_load_lds(
            (const __attribute__((address_space(1))) void*)gp,
            (__attribute__((address_space(3))) void*)lp, 16, 0, 0);
      }
    }
    __syncthreads();

#pragma unroll
    for (int kk = 0; kk < 2; ++kk) {
      short8 a[4], b[4];
#pragma unroll
      for (int mi = 0; mi < 4; ++mi) {
        const int row = wr * 64 + mi * 16 + rl;
        const int slot = (kk * 4 + g) ^ (row & 7);
        a[mi] = *(const short8*)&As[row * 64 + slot * 8];
      }
#pragma unroll
      for (int ni = 0; ni < 4; ++ni) {
        const int row = wc * 64 + ni * 16 + rl;
        const int slot = (kk * 4 + g) ^ (row & 7);
        b[ni] = *(const short8*)&Bs[row * 64 + slot * 8];
      }
#pragma unroll
      for (int mi = 0; mi < 4; ++mi)
#pragma unroll
        for (int ni = 0; ni < 4; ++ni)
          acc[mi][ni] = __builtin_amdgcn_mfma_f32_16x16x32_bf16(
              a[mi], b[ni], acc[mi][ni], 0, 0, 0);
    }
    __syncthreads();
  }

#pragma unroll
  for (int mi = 0; mi < 4; ++mi) {
#pragma unroll
    for (int j = 0; j < 4; ++j) {
      const int row = bm + wr * 64 + mi * 16 + g * 4 + j;
      if (row >= M) continue;
#pragma unroll
      for (int ni = 0; ni < 4; ++ni) {
        const int col = wc * 64 + ni * 16 + rl;
        float v = acc[mi][ni][j];
        if (ADD_BIAS) v += bias[col];
        const size_t idx = (size_t)row * ldc + col;
        if (OUT_MODE == 0) {
          Cf[idx] = v;
        } else if (OUT_MODE == 1) {
          Cb[idx] = f2bf(v);
        } else {
          v += Cf[idx];
          Cf[idx] = v;
          Cb[idx] = f2bf(v);
        }
      }
    }
  }
}

// ===========================================================================
// FUSED PATH: z-gather. One wave per bucket (r,v): Z[v, r*256:] = sum of x
// rows (x lives at xrow = Z + v*KBIG + 2048). Empty buckets write zeros.
// ===========================================================================
__global__ __launch_bounds__(256) void zgather_kernel(
    unsigned short* __restrict__ Z, const int* __restrict__ idx,
    const int* __restrict__ offs_base, const int* __restrict__ sorted) {
  const int b = blockIdx.x * 4 + (threadIdx.x >> 6);  // 0..239999
  if (b >= NUM_RELS * N_NODES) return;
  const int lane = threadIdx.x & 63;
  const int r = b / N_NODES;
  const int v = b - r * N_NODES;
  const int s = offs_base[b], e = offs_base[b + 1];

  float ax = 0.f, ay = 0.f, az = 0.f, aw = 0.f;
  for (int i = s; i < e; ++i) {
    const int node = idx[sorted[i]];
    const ushort4 t = *reinterpret_cast<const ushort4*>(
        &Z[(size_t)node * KBIG + 2048 + lane * 4]);
    ax += bf2f(t.x); ay += bf2f(t.y); az += bf2f(t.z); aw += bf2f(t.w);
  }
  ushort4 o;
  o.x = f2bf(ax); o.y = f2bf(ay); o.z = f2bf(az); o.w = f2bf(aw);
  *reinterpret_cast<ushort4*>(&Z[(size_t)v * KBIG + r * 256 + lane * 4]) = o;
}

// ===========================================================================
// FUSED PATH: DistMult scoring from bf16 h copy (halved gather bytes).
// ===========================================================================
__global__ __launch_bounds__(256) void score_bf16_kernel(
    const unsigned short* __restrict__ hb, const float* __restrict__ wrel,
    const int* __restrict__ ts, const int* __restrict__ tr,
    const int* __restrict__ to, float* __restrict__ out, int T) {
  const int t = blockIdx.x * 4 + (threadIdx.x >> 6);
  if (t >= T) return;
  const int lane = threadIdx.x & 63;
  const int s = ts[t];
  const int r = tr[t];
  const int o = to[t];
  const ushort4 hs =
      *reinterpret_cast<const ushort4*>(&hb[(size_t)s * DDIM + lane * 4]);
  const ushort4 ho =
      *reinterpret_cast<const ushort4*>(&hb[(size_t)o * DDIM + lane * 4]);
  const float4 wr =
      *reinterpret_cast<const float4*>(&wrel[(size_t)r * DDIM + lane * 4]);
  float sum = bf2f(hs.x) * wr.x * bf2f(ho.x) + bf2f(hs.y) * wr.y * bf2f(ho.y) +
              bf2f(hs.z) * wr.z * bf2f(ho.z) + bf2f(hs.w) * wr.w * bf2f(ho.w);
#pragma unroll
  for (int off = 32; off; off >>= 1) sum += __shfl_down(sum, off, 64);
  if (lane == 0) out[t] = sum;
}

// ===========================================================================
// FALLBACK PATH (round-3, proven): 256-thread GEMM + per-rel gather + fp32
// score. Used only if ws_size is too small for the fused layout.
// ===========================================================================
template <int OUT_BF16, int ADD_BIAS>
__global__ __launch_bounds__(256) void mfma_gemm_kernel(
    const unsigned short* __restrict__ A, const unsigned short* __restrict__ Bt,
    const float* __restrict__ bias, void* __restrict__ C, int M, int K) {
  __shared__ __align__(16) unsigned short As[128 * 64];
  __shared__ __align__(16) unsigned short Bs[128 * 64];

  const int tid = threadIdx.x;
  const int lane = tid & 63;
  const int wave = tid >> 6;
  const int bm = blockIdx.y * 128;
  const int bn = blockIdx.x * 128;
  const int wr = wave >> 1;
  const int wc = wave & 1;

  f32x4 acc[4][4];
#pragma unroll
  for (int i = 0; i < 4; ++i)
#pragma unroll
    for (int j = 0; j < 4; ++j) acc[i][j] = (f32x4){0.f, 0.f, 0.f, 0.f};

  const int g = lane >> 4;
  const int rl = lane & 15;

  for (int k0 = 0; k0 < K; k0 += 64) {
#pragma unroll
    for (int c = 0; c < 8; ++c) {
      const int chunk = c * 4 + wave;
      if (chunk < 16) {
        const int S = chunk * 64 + lane;
        const int row = S >> 3;
        const int s = S & 7;
        int grow = bm + row;
        if (grow > M - 1) grow = M - 1;
        const int kcol = k0 + ((s ^ (row & 7)) << 3);
        const unsigned short* gp = A + (size_t)grow * K + kcol;
        unsigned short* lp = As + (size_t)chunk * 512;
        __builtin_amdgcn_global_load_lds(
            (const __attribute__((address_space(1))) void*)gp,
            (__attribute__((address_space(3))) void*)lp, 16, 0, 0);
      } else {
        const int S = (chunk - 16) * 64 + lane;
        const int row = S >> 3;
        const int s = S & 7;
        const int kcol = k0 + ((s ^ (row & 7)) << 3);
        const unsigned short* gp = Bt + (size_t)(bn + row) * K + kcol;
        unsigned short* lp = Bs + (size_t)(chunk - 16) * 512;
        __builtin_amdgcn_global_load_lds(
            (const __attribute__((address_space(1))) void*)gp,
            (__attribute__((address_space(3))) void*)lp, 16, 0, 0);
      }
    }
    __syncthreads();

#pragma unroll
    for (int kk = 0; kk < 2; ++kk) {
      short8 a[4], b[4];
#pragma unroll
      for (int mi = 0; mi < 4; ++mi) {
        const int row = wr * 64 + mi * 16 + rl;
        const int slot = (kk * 4 + g) ^ (row & 7);
        a[mi] = *(const short8*)&As[row * 64 + slot * 8];
      }
#pragma unroll
      for (int ni = 0; ni < 4; ++ni) {
        const int row = wc * 64 + ni * 16 + rl;
        const int slot = (kk * 4 + g) ^ (row & 7);
        b[ni] = *(const short8*)&Bs[row * 64 + slot * 8];
      }
#pragma unroll
      for (int mi = 0; mi < 4; ++mi)
#pragma unroll
        for (int ni = 0; ni < 4; ++ni)
          acc[mi][ni] = __builtin_amdgcn_mfma_f32_16x16x32_bf16(
              a[mi], b[ni], acc[mi][ni], 0, 0, 0);
    }
    __syncthreads();
  }

#pragma unroll
  for (int mi = 0; mi < 4; ++mi) {
#pragma unroll
    for (int j = 0; j < 4; ++j) {
      const int row = bm + wr * 64 + mi * 16 + g * 4 + j;
      if (row >= M) continue;
#pragma unroll
      for (int ni = 0; ni < 4; ++ni) {
        const int col = bn + wc * 64 + ni * 16 + rl;
        float v = acc[mi][ni][j];
        if (ADD_BIAS) v += bias[col];
        if (OUT_BF16)
          ((unsigned short*)C)[(size_t)row * DDIM + col] = f2bf(v);
        else
          ((float*)C)[(size_t)row * DDIM + col] = v;
      }
    }
  }
}

__global__ __launch_bounds__(256) void gather_kernel(
    const unsigned short* __restrict__ yf, const unsigned short* __restrict__ yb,
    const int* __restrict__ src, const int* __restrict__ dst,
    const int* __restrict__ offs, const int* __restrict__ sorted, int rel,
    float* __restrict__ h) {
  const int v = blockIdx.x * 4 + (threadIdx.x >> 6);
  if (v >= N_NODES) return;
  const int lane = threadIdx.x & 63;
  const int kf = rel * N_NODES + v;
  const int kb = NUM_RELS * N_NODES + rel * N_NODES + v;
  const int sf = offs[kf], ef = offs[kf + 1];
  const int sb = offs[kb], eb = offs[kb + 1];
  if (sf == ef && sb == eb) return;

  float ax = 0.f, ay = 0.f, az = 0.f, aw = 0.f;
  for (int i = sf; i < ef; ++i) {
    const int e = sorted[i];
    const ushort4 t =
        *reinterpret_cast<const ushort4*>(&yf[(size_t)src[e] * DDIM + lane * 4]);
    ax += bf2f(t.x); ay += bf2f(t.y); az += bf2f(t.z); aw += bf2f(t.w);
  }
  for (int i = sb; i < eb; ++i) {
    const int e = sorted[i];
    const ushort4 t =
        *reinterpret_cast<const ushort4*>(&yb[(size_t)dst[e] * DDIM + lane * 4]);
    ax += bf2f(t.x); ay += bf2f(t.y); az += bf2f(t.z); aw += bf2f(t.w);
  }
  float4* hp = reinterpret_cast<float4*>(&h[(size_t)v * DDIM + lane * 4]);
  float4 hv = *hp;
  hv.x += ax; hv.y += ay; hv.z += az; hv.w += aw;
  *hp = hv;
}

__global__ __launch_bounds__(256) void score_kernel(
    const float* __restrict__ h, const float* __restrict__ wrel,
    const int* __restrict__ ts, const int* __restrict__ tr,
    const int* __restrict__ to, float* __restrict__ out, int T) {
  const int t = blockIdx.x * 4 + (threadIdx.x >> 6);
  if (t >= T) return;
  const int lane = threadIdx.x & 63;
  const int s = ts[t];
  const int r = tr[t];
  const int o = to[t];
  const float4 hs =
      *reinterpret_cast<const float4*>(&h[(size_t)s * DDIM + lane * 4]);
  const float4 ho =
      *reinterpret_cast<const float4*>(&h[(size_t)o * DDIM + lane * 4]);
  const float4 wr =
      *reinterpret_cast<const float4*>(&wrel[(size_t)r * DDIM + lane * 4]);
  float sum = hs.x * wr.x * ho.x + hs.y * wr.y * ho.y + hs.z * wr.z * ho.z +
              hs.w * wr.w * ho.w;
#pragma unroll
  for (int off = 32; off; off >>= 1) sum += __shfl_down(sum, off, 64);
  if (lane == 0) out[t] = sum;
}

// ===========================================================================
extern "C" void kernel_launch(void* const* d_in, const int* in_sizes, int n_in,
                              void* d_out, int out_size, void* d_ws,
                              size_t ws_size, hipStream_t stream) {
  const float* feats = (const float*)d_in[0];
  const float* W_affine = (const float*)d_in[1];
  const float* b_affine = (const float*)d_in[2];
  const float* W_fwd = (const float*)d_in[3];
  const float* W_bwd = (const float*)d_in[4];
  const float* W_loop = (const float*)d_in[5];
  const float* w_relation = (const float*)d_in[6];
  const int* src = (const int*)d_in[7];
  const int* dst = (const int*)d_in[8];
  const int* etype = (const int*)d_in[9];
  const int* trip_s = (const int*)d_in[10];
  const int* trip_r = (const int*)d_in[11];
  const int* trip_o = (const int*)d_in[12];

  float* out_w = (float*)d_out;  // [N_TRIP]
  float* h = out_w + N_TRIP;     // [N_NODES * D] fp32

  if (ws_size >= 172000000ULL) {
    // ------------------- FUSED PATH -------------------
    char* ws = (char*)d_ws;
    unsigned short* fb = (unsigned short*)(ws);                // 7,680,000
    unsigned short* Z = (unsigned short*)(ws + 7680000);       // 138,240,000
    unsigned short* Wta = (unsigned short*)(ws + 145920000);   // 65,536
    unsigned short* Wcat1 = (unsigned short*)(ws + 145985536); // 1,179,648
    unsigned short* Wcat2 = (unsigned short*)(ws + 147165184); // 1,048,576
    unsigned short* hbf = (unsigned short*)(ws + 148213760);   // 15,360,000
    int* cnt = (int*)(ws + 163573760);                         // 1,921,024
    int* offs = (int*)(ws + 165494784);                        // 1,921,024
    int* cur = (int*)(ws + 167415808);                         // 1,921,024
    int* bsum = (int*)(ws + 169336832);                        // 2,048
    int* sorted = (int*)(ws + 169338880);                      // 2,400,000

    // bucket build
    zero_int_kernel<<<(NPAD + 255) / 256, 256, 0, stream>>>(cnt, NPAD);
    hist_kernel<<<(N_EDGES + 255) / 256, 256, 0, stream>>>(src, dst, etype, cnt);
    scan1_kernel<<<NCHUNK, 256, 0, stream>>>(cnt, offs, bsum);
    scan2_kernel<<<1, 512, 0, stream>>>(bsum);
    scan3_kernel<<<(NPAD + 255) / 256, 256, 0, stream>>>(offs, bsum, cur);
    fill_kernel<<<(N_EDGES + 255) / 256, 256, 0, stream>>>(src, dst, etype,
                                                           cur, sorted);
    // conversions
    convert_bf16_kernel<<<(N_NODES * F_RAW + 255) / 256, 256, 0, stream>>>(
        feats, fb, N_NODES * F_RAW);
    transpose_bf16_kernel<<<(F_RAW * DDIM + 255) / 256, 256, 0, stream>>>(
        W_affine, Wta, 1, F_RAW, DDIM);
    build_wcat_kernel<<<(256 * KBIG + 255) / 256, 256, 0, stream>>>(
        W_fwd, W_loop, Wcat1, KBIG);
    build_wcat_kernel<<<(256 * KBWD + 255) / 256, 256, 0, stream>>>(
        W_bwd, nullptr, Wcat2, KBWD);

    const int ngrid = (N_NODES + 127) / 128;  // 235

    // x (bf16) -> Z columns [2048..2304)
    gemm256_kernel<1, 1><<<ngrid, 512, 0, stream>>>(
        fb, F_RAW, F_RAW, Wta, b_affine, nullptr, Z + 2048, KBIG, N_NODES);
    // z_fwd: Z cols [0..2048)
    zgather_kernel<<<(NUM_RELS * N_NODES + 3) / 4, 256, 0, stream>>>(
        Z, src, offs, sorted);
    // h = [Z_fwd | x] @ [W_fwd stack ; W_loop]
    gemm256_kernel<0, 0><<<ngrid, 512, 0, stream>>>(
        Z, KBIG, KBIG, Wcat1, nullptr, h, nullptr, DDIM, N_NODES);
    // z_bwd overwrites Z cols [0..2048)
    zgather_kernel<<<(NUM_RELS * N_NODES + 3) / 4, 256, 0, stream>>>(
        Z, dst, offs + NUM_RELS * N_NODES, sorted);
    // h += Z_bwd @ [W_bwd stack]; also emit hbf
    gemm256_kernel<2, 0><<<ngrid, 512, 0, stream>>>(
        Z, KBIG, KBWD, Wcat2, nullptr, h, hbf, DDIM, N_NODES);
    // scoring from bf16 h
    score_bf16_kernel<<<(N_TRIP + 3) / 4, 256, 0, stream>>>(
        hbf, w_relation, trip_s, trip_r, trip_o, out_w, N_TRIP);
    return;
  }

  // ------------------- FALLBACK (round-3) -------------------
  char* ws = (char*)d_ws;
  unsigned short* fb = (unsigned short*)(ws);
  unsigned short* xb = (unsigned short*)(ws + 7680000);
  unsigned short* yf = (unsigned short*)(ws + 23040000);
  unsigned short* yb = (unsigned short*)(ws + 38400000);
  unsigned short* Wta = (unsigned short*)(ws + 53760000);
  unsigned short* Wtf = (unsigned short*)(ws + 53825536);
  unsigned short* Wtb = (unsigned short*)(ws + 54874112);
  unsigned short* Wtl = (unsigned short*)(ws + 55922688);
  int* cnt = (int*)(ws + 56053760);
  int* offs = (int*)(ws + 57974784);
  int* cur = (int*)(ws + 59895808);
  int* bsum = (int*)(ws + 61816832);
  int* sorted = (int*)(ws + 61818880);

  zero_int_kernel<<<(NPAD + 255) / 256, 256, 0, stream>>>(cnt, NPAD);
  hist_kernel<<<(N_EDGES + 255) / 256, 256, 0, stream>>>(src, dst, etype, cnt);
  scan1_kernel<<<NCHUNK, 256, 0, stream>>>(cnt, offs, bsum);
  scan2_kernel<<<1, 512, 0, stream>>>(bsum);
  scan3_kernel<<<(NPAD + 255) / 256, 256, 0, stream>>>(offs, bsum, cur);
  fill_kernel<<<(N_EDGES + 255) / 256, 256, 0, stream>>>(src, dst, etype, cur,
                                                         sorted);

  convert_bf16_kernel<<<(N_NODES * F_RAW + 255) / 256, 256, 0, stream>>>(
      feats, fb, N_NODES * F_RAW);
  transpose_bf16_kernel<<<(F_RAW * DDIM + 255) / 256, 256, 0, stream>>>(
      W_affine, Wta, 1, F_RAW, DDIM);
  transpose_bf16_kernel<<<(NUM_RELS * DDIM * DDIM + 255) / 256, 256, 0,
                          stream>>>(W_fwd, Wtf, NUM_RELS, DDIM, DDIM);
  transpose_bf16_kernel<<<(NUM_RELS * DDIM * DDIM + 255) / 256, 256, 0,
                          stream>>>(W_bwd, Wtb, NUM_RELS, DDIM, DDIM);
  transpose_bf16_kernel<<<(DDIM * DDIM + 255) / 256, 256, 0, stream>>>(
      W_loop, Wtl, 1, DDIM, DDIM);

  const dim3 ggrid(DDIM / 128, (N_NODES + 127) / 128);

  mfma_gemm_kernel<1, 1><<<ggrid, 256, 0, stream>>>(fb, Wta, b_affine, xb,
                                                    N_NODES, F_RAW);
  mfma_gemm_kernel<0, 0><<<ggrid, 256, 0, stream>>>(xb, Wtl, nullptr, h,
                                                    N_NODES, DDIM);

  const int gat_grid = (N_NODES + 3) / 4;
  for (int r = 0; r < NUM_RELS; ++r) {
    mfma_gemm_kernel<1, 0><<<ggrid, 256, 0, stream>>>(
        xb, Wtf + (size_t)r * DDIM * DDIM, nullptr, yf, N_NODES, DDIM);
    mfma_gemm_kernel<1, 0><<<ggrid, 256, 0, stream>>>(
        xb, Wtb + (size_t)r * DDIM * DDIM, nullptr, yb, N_NODES, DDIM);
    gather_kernel<<<gat_grid, 256, 0, stream>>>(yf, yb, src, dst, offs, sorted,
                                                r, h);
  }

  score_kernel<<<(N_TRIP + 3) / 4, 256, 0, stream>>>(
      h, w_relation, trip_s, trip_r, trip_o, out_w, N_TRIP);
}